// Round 9
// baseline (719.649 us; speedup 1.0000x reference)
//
#include <hip/hip_runtime.h>
#include <math.h>

#define N_TOKENS 16384
#define D_MODEL  4096
#define N_EXP    64

#define TOKB 64                  // tokens per block (lane = token)
#define NWV  16                  // waves per block (1024 threads)
#define NSL  8                   // k-slices (one per wave-pair)
#define KSL  (D_MODEL / NSL)     // 512 k per slice
#define BK   16                  // k per chunk
#define NCH  (KSL / BK)          // 32 chunks
#define XLD  66                  // LDS x-tile k-row stride (64 + 2: conflict-free)
#define SLSZ (2 * BK * XLD)      // 2112 floats per slice (double-buffered)
#define NBLK (N_TOKENS / TOKB)   // 256 blocks = 1/CU -> 16 waves/CU = 4/SIMD

// ---------------------------------------------------------------------------
// Pre-pass: w[64][4096] -> wT[4096][64] (k-major): per-k expert-half is 32
// uniform consecutive floats -> s_load_dwordx16 pairs from L2-hot 1 MB.
// ---------------------------------------------------------------------------
__global__ void __launch_bounds__(256)
transpose_w(const float* __restrict__ w, float* __restrict__ wt) {
    __shared__ float t[64][65];
    const int k0 = blockIdx.x * 64;
    const int kc = (threadIdx.x & 15) * 4;
    const int e0 = threadIdx.x >> 4;         // 0..15
#pragma unroll
    for (int p = 0; p < 4; ++p) {
        int e = p * 16 + e0;
        float4 v = *(const float4*)(w + (size_t)e * D_MODEL + k0 + kc);
        t[kc + 0][e] = v.x; t[kc + 1][e] = v.y;
        t[kc + 2][e] = v.z; t[kc + 3][e] = v.w;
    }
    __syncthreads();
    const int kr = threadIdx.x >> 2;         // 0..63
    const int ec = (threadIdx.x & 3) * 16;
#pragma unroll
    for (int j = 0; j < 4; ++j) {
        float4 v = make_float4(t[kr][ec + j * 4 + 0], t[kr][ec + j * 4 + 1],
                               t[kr][ec + j * 4 + 2], t[kr][ec + j * 4 + 3]);
        *(float4*)(wt + (size_t)(k0 + kr) * N_EXP + ec + j * 4) = v;
    }
}

// ---------------------------------------------------------------------------
// Fused router: lane = token, w via scalar pipe, x via LDS (round-8 fix).
// Round 8's per-lane x loads were 64-line gathers (lane stride = 16 KB) and
// the compiler dropped the x double-buffer (VGPR=52 < 64 needed) -> 38% VALU.
// Now: the wave-pair owning k-slice s stages x[64 tok][16 k] into LDS with
// COALESCED float4 loads (16 lines/instr), layout [k][66]:
//   - compute read: per k one ds_read_b32, 64 lanes stride-1 (2-way, free)
//   - staging write: 4x b32, banks (2kc+2i+t)%32 -> uniform 2-way, free
// Inner k-row: 1 ds_read_b32 + 32 v_fmac(v_acc, s_w, v_x); w row = 32
// uniform floats via s_load from L2-hot wT. LDS pipe ~36% of FMA wall,
// scalar pipe separate from both -> VALU is the binding resource.
// One barrier per chunk (double-buffer, pair-local staging).
// Epilogue: slice tree-reduce 8->4->2->1 in LDS (reuse staging region),
// ballot-argmax softmax/top-2 (ties -> lowest index), per-block p/f sums.
// ---------------------------------------------------------------------------
__global__ void __launch_bounds__(1024)
router_fused(const float* __restrict__ x, const float* __restrict__ wt,
             float* __restrict__ out, float* __restrict__ block_sums) {
    __shared__ float smem[NSL * SLSZ];   // 16896 floats = 67584 B

    const int tid  = threadIdx.x;
    const int wid  = tid >> 6;
    const int lane = tid & 63;           // token within block (main loop)
    const int tok0 = blockIdx.x * TOKB;

    const int wid_u = __builtin_amdgcn_readfirstlane(wid);
    const int h = wid_u & 1;             // expert half: experts h*32..h*32+31
    const int s = wid_u >> 1;            // k-slice: k in [s*512, s*512+512)

    float* xsl = smem + s * SLSZ;        // this slice's x double-buffer

    // staging decomposition within the 128-thread slice pair:
    // float4 idx = p + 128*j -> token t0+32j, k-chunk kc..kc+3
    const int p  = tid & 127;
    const int t0 = p >> 2;               // 0..31
    const int kc = (p & 3) * 4;          // 0,4,8,12

    const float* wr = wt + (size_t)s * KSL * N_EXP + h * 32;   // uniform
    const float* xgb = x + (size_t)(tok0 + t0) * D_MODEL + s * KSL + kc;

    float acc[32] = {};

    // prologue: stage chunk 0 into buffer 0
    {
        float4 v0 = *(const float4*)(xgb);
        float4 v1 = *(const float4*)(xgb + (size_t)32 * D_MODEL);
#pragma unroll
        for (int i = 0; i < 4; ++i) {
            xsl[(kc + i) * XLD + t0]      = ((const float*)&v0)[i];
            xsl[(kc + i) * XLD + t0 + 32] = ((const float*)&v1)[i];
        }
    }
    __syncthreads();

    int cur = 0;
#pragma unroll 1
    for (int g = 0; g < NCH; ++g) {
        float4 v0, v1;
        if (g + 1 < NCH) {               // issue next chunk's loads early
            const float* xg = xgb + (g + 1) * BK;
            v0 = *(const float4*)(xg);
            v1 = *(const float4*)(xg + (size_t)32 * D_MODEL);
        }

        const float* xb = xsl + cur * (BK * XLD) + lane;
        const float* wg = wr + (size_t)g * BK * N_EXP;
#pragma unroll
        for (int k = 0; k < BK; ++k) {
            const float xk = xb[k * XLD];              // ds_read_b32, stride-1
            const float* wk = wg + (size_t)k * N_EXP;  // uniform -> s_load
#pragma unroll
            for (int e = 0; e < 32; ++e)
                acc[e] = fmaf(wk[e], xk, acc[e]);
        }

        if (g + 1 < NCH) {
            float* bn = xsl + (cur ^ 1) * (BK * XLD);
#pragma unroll
            for (int i = 0; i < 4; ++i) {
                bn[(kc + i) * XLD + t0]      = ((const float*)&v0)[i];
                bn[(kc + i) * XLD + t0 + 32] = ((const float*)&v1)[i];
            }
        }
        __syncthreads();
        cur ^= 1;
    }

    // ---- epilogue: slice tree-reduce 8 -> 4 -> 2 -> 1 (tiles [64][33]) ----
    if (s >= 4) {
        float* tp = smem + (((s - 4) * 2 + h) * 64 + lane) * 33;
#pragma unroll
        for (int e = 0; e < 32; ++e) tp[e] = acc[e];
    }
    __syncthreads();
    if (s < 4) {
        const float* tp = smem + ((s * 2 + h) * 64 + lane) * 33;
#pragma unroll
        for (int e = 0; e < 32; ++e) acc[e] += tp[e];
    }
    __syncthreads();
    if (s == 2 || s == 3) {
        float* tp = smem + (((s - 2) * 2 + h) * 64 + lane) * 33;
#pragma unroll
        for (int e = 0; e < 32; ++e) tp[e] = acc[e];
    }
    __syncthreads();
    if (s < 2) {
        const float* tp = smem + ((s * 2 + h) * 64 + lane) * 33;
#pragma unroll
        for (int e = 0; e < 32; ++e) acc[e] += tp[e];
    }
    __syncthreads();
    if (s == 1) {
        float* tp = smem + (h * 64 + lane) * 33;
#pragma unroll
        for (int e = 0; e < 32; ++e) tp[e] = acc[e];
    }
    __syncthreads();
    float* flog = smem + 8448;           // [64][65] final logits (slots 4-7 dead)
    if (s == 0) {
        const float* tp = smem + (h * 64 + lane) * 33;
#pragma unroll
        for (int e = 0; e < 32; ++e)
            flog[lane * 65 + h * 32 + e] = acc[e] + tp[e];
    }
    __syncthreads();

    // ---- softmax/top-2: lane = expert, wave wid handles 4 tokens ----
    float p_acc = 0.f, f_acc = 0.f;
#pragma unroll 1
    for (int it = 0; it < 4; ++it) {
        const int tl = wid * 4 + it;
        float logit = flog[tl * 65 + lane];

        // top-1: value max-reduce, then ballot -> lowest tied index
        float m = logit;
#pragma unroll
        for (int off = 32; off; off >>= 1)
            m = fmaxf(m, __shfl_xor(m, off, 64));
        unsigned long long b1 = __ballot(logit == m);
        int i1 = __ffsll(b1) - 1;

        float pr = expf(logit - m);
        float denom = pr;
#pragma unroll
        for (int off = 32; off; off >>= 1)
            denom += __shfl_xor(denom, off, 64);

        p_acc += pr / denom;             // router_probs[token][lane]
        if (lane == i1) f_acc += 1.f;

        // top-2: mask i1, repeat
        float lx = (lane == i1) ? -__builtin_inff() : logit;
        float m2 = lx;
#pragma unroll
        for (int off = 32; off; off >>= 1)
            m2 = fmaxf(m2, __shfl_xor(m2, off, 64));
        unsigned long long b2 = __ballot(lx == m2);
        int i2 = __ffsll(b2) - 1;

        if (lane == 0) {
            float p1 = 1.0f / denom;             // exp(m-m)/denom
            float p2 = expf(m2 - m) / denom;
            float s12 = p1 + p2;
            int token = tok0 + tl;
            ((float2*)out)[token] = make_float2(p1 / s12, p2 / s12);
            ((float2*)(out + 2 * N_TOKENS))[token] =
                make_float2((float)i1, (float)i2);
        }
    }

    // block-level p/f sums -> block_sums (no atomics)
    float* pf = smem + 12608;            // 2048 floats, dead region
    pf[wid * 64 + lane]        = p_acc;
    pf[1024 + wid * 64 + lane] = f_acc;
    __syncthreads();
    if (tid < N_EXP) {
        float ps = 0.f, fs = 0.f;
#pragma unroll
        for (int hh = 0; hh < NWV; ++hh) {
            ps += pf[hh * 64 + tid];
            fs += pf[1024 + hh * 64 + tid];
        }
        block_sums[(size_t)blockIdx.x * 128 + tid]      = ps;
        block_sums[(size_t)blockIdx.x * 128 + 64 + tid] = fs;
    }
}

// ---------------------------------------------------------------------------
// Final: reduce 256 blocks' p/f sums, loss = 0.01 * sum_e (f_e/N)*(p_e/N).
// ---------------------------------------------------------------------------
__global__ void __launch_bounds__(256)
router_final(const float* __restrict__ block_sums, float* __restrict__ out) {
    __shared__ float sp[4][N_EXP];
    __shared__ float sf[4][N_EXP];

    int tid  = threadIdx.x;
    int wv   = tid >> 6;
    int lane = tid & 63;

    float ps = 0.f, fs = 0.f;
#pragma unroll 8
    for (int b = wv * (NBLK / 4); b < (wv + 1) * (NBLK / 4); ++b) {
        ps += block_sums[(size_t)b * 128 + lane];
        fs += block_sums[(size_t)b * 128 + 64 + lane];
    }
    sp[wv][lane] = ps;
    sf[wv][lane] = fs;
    __syncthreads();

    if (tid < N_EXP) {
        float pt = sp[0][tid] + sp[1][tid] + sp[2][tid] + sp[3][tid];
        float ft = sf[0][tid] + sf[1][tid] + sf[2][tid] + sf[3][tid];
        float v = pt * ft;
#pragma unroll
        for (int off = 1; off < 64; off <<= 1)
            v += __shfl_xor(v, off, 64);
        if (tid == 0)
            out[4 * N_TOKENS] = 0.01f * v / ((float)N_TOKENS * (float)N_TOKENS);
    }
}

// ---------------------------------------------------------------------------
extern "C" void kernel_launch(void* const* d_in, const int* in_sizes, int n_in,
                              void* d_out, int out_size, void* d_ws, size_t ws_size,
                              hipStream_t stream) {
    (void)in_sizes; (void)n_in; (void)out_size; (void)ws_size;
    const float* x = (const float*)d_in[0];
    const float* w = (const float*)d_in[1];
    float* out = (float*)d_out;

    float* wT = (float*)d_ws;                            // 4096*64*4 = 1 MB
    float* block_sums = wT + (size_t)D_MODEL * N_EXP;    // 256*128*4 = 128 KB

    transpose_w<<<D_MODEL / 64, 256, 0, stream>>>(w, wT);
    router_fused<<<NBLK, 1024, 0, stream>>>(x, wT, out, block_sums);
    router_final<<<1, 256, 0, stream>>>(block_sums, out);
}